// Round 4
// baseline (371.301 us; speedup 1.0000x reference)
//
#include <hip/hip_runtime.h>
#include <hip/hip_bf16.h>

#define SCALE 0.07216878364870322f   // (3*64)^-0.5
#define LOG2E 1.4426950408889634f
// Q is pre-scaled by SCALE*LOG2E so attention logits are in log2 units.

typedef __bf16 bf16x8 __attribute__((ext_vector_type(8)));
typedef float f32x16 __attribute__((ext_vector_type(16)));
typedef float f32x4v __attribute__((ext_vector_type(4)));
typedef unsigned int u32x4 __attribute__((ext_vector_type(4)));
typedef unsigned short u16;

#define MFMA(a, b, c) __builtin_amdgcn_mfma_f32_32x32x16_bf16(a, b, c, 0, 0, 0)

__device__ __forceinline__ u16 b16(float v) { return __builtin_bit_cast(u16, (__bf16)v); }
__device__ __forceinline__ float fb16(u16 u) {
    unsigned int t = (unsigned int)u << 16;
    return __builtin_bit_cast(float, t);
}
__device__ __forceinline__ unsigned int splitpack(float v) {
    u16 h = b16(v);
    float r = v - fb16(h);
    return (unsigned int)h | ((unsigned int)b16(r) << 16);
}
__device__ __forceinline__ unsigned int pack2(float a, float b) {
    return (unsigned int)b16(a) | ((unsigned int)b16(b) << 16);
}

// ---------------- K1: QKV projection, MFMA split-bf16, zero-LDS main loop ----
__global__ __launch_bounds__(256) void qkv_mfma(const float* __restrict__ x,
                                                const float* __restrict__ wq,
                                                u16* __restrict__ Qhi, u16* __restrict__ Qlo,
                                                u16* __restrict__ Khi, u16* __restrict__ Klo,
                                                u16* __restrict__ Vf) {
    __shared__ unsigned int ldsr[2][32][196];
    const int tid = threadIdx.x;
    const int lane = tid & 63, w = tid >> 6, hf = lane >> 5, l31 = lane & 31;
    const int o0 = blockIdx.x * 64;
    const int n0 = blockIdx.y * 128;
    const int b = blockIdx.z;
    const int nw0 = n0 + w * 32;
    const int part = o0 >> 9;
    const int h = (o0 >> 6) & 7;
    const int bh = b * 8 + h;

    const float* xp = x + ((size_t)(b * 2048 + nw0 + l31)) * 768 + hf * 24;
    const float* wp0 = wq + (size_t)(o0 + l31) * 256 + hf * 8;
    const float* wp1 = wp0 + 32 * 256;

    f32x16 acc[3][2] = {};
    #pragma unroll 2
    for (int k0 = 0; k0 < 16; ++k0) {
        float xf[24], wf0[8], wf1[8];
        #pragma unroll
        for (int q = 0; q < 6; ++q) {
            f32x4v t = *(const f32x4v*)(xp + k0 * 48 + q * 4);
            xf[q * 4 + 0] = t[0]; xf[q * 4 + 1] = t[1];
            xf[q * 4 + 2] = t[2]; xf[q * 4 + 3] = t[3];
        }
        {
            f32x4v t0 = *(const f32x4v*)(wp0 + k0 * 16);
            f32x4v t1 = *(const f32x4v*)(wp0 + k0 * 16 + 4);
            f32x4v t2 = *(const f32x4v*)(wp1 + k0 * 16);
            f32x4v t3 = *(const f32x4v*)(wp1 + k0 * 16 + 4);
            #pragma unroll
            for (int e = 0; e < 4; ++e) {
                wf0[e] = t0[e]; wf0[4 + e] = t1[e];
                wf1[e] = t2[e]; wf1[4 + e] = t3[e];
            }
        }
        bf16x8 xh[3], xl[3], wh[2], wl[2];
        #pragma unroll
        for (int c = 0; c < 3; ++c)
            #pragma unroll
            for (int e = 0; e < 8; ++e) {
                float v = xf[e * 3 + c];
                __bf16 hi = (__bf16)v;
                xh[c][e] = hi;
                xl[c][e] = (__bf16)(v - (float)hi);
            }
        #pragma unroll
        for (int e = 0; e < 8; ++e) {
            { float v = wf0[e]; __bf16 hi = (__bf16)v; wh[0][e] = hi; wl[0][e] = (__bf16)(v - (float)hi); }
            { float v = wf1[e]; __bf16 hi = (__bf16)v; wh[1][e] = hi; wl[1][e] = (__bf16)(v - (float)hi); }
        }
        #pragma unroll
        for (int c = 0; c < 3; ++c)
            #pragma unroll
            for (int ot = 0; ot < 2; ++ot) {
                acc[c][ot] = MFMA(xh[c], wh[ot], acc[c][ot]);
                acc[c][ot] = MFMA(xl[c], wh[ot], acc[c][ot]);
                acc[c][ot] = MFMA(xh[c], wl[ot], acc[c][ot]);
            }
    }

    #pragma unroll
    for (int round = 0; round < 2; ++round) {
        __syncthreads();
        if ((w >> 1) == round) {
            unsigned int (*L)[196] = ldsr[w & 1];
            #pragma unroll
            for (int c = 0; c < 3; ++c)
                #pragma unroll
                for (int ot = 0; ot < 2; ++ot)
                    #pragma unroll
                    for (int r = 0; r < 16; ++r) {
                        float v = acc[c][ot][r];
                        if (part == 0) v *= (SCALE * LOG2E);
                        int nn = (r & 3) + 8 * (r >> 2) + 4 * hf;
                        int dcol = 3 * (ot * 32 + l31) + c;
                        L[nn][dcol] = (part == 2) ? (unsigned int)b16(v) : splitpack(v);
                    }
            if (part < 2) {
                const int itqw = blockIdx.y * 4 + w;
                u16* bhp = (part == 0 ? Qhi : Khi) + (size_t)bh * 393216 + itqw * 6144 + lane * 8;
                u16* blp = (part == 0 ? Qlo : Klo) + (size_t)bh * 393216 + itqw * 6144 + lane * 8;
                #pragma unroll
                for (int ks = 0; ks < 12; ++ks) {
                    const unsigned int* p = &L[l31][ks * 16 + hf * 8];
                    u32x4 a = *(const u32x4*)p;
                    u32x4 bq = *(const u32x4*)(p + 4);
                    u32x4 hi = { (a[0] & 0xffffu) | (a[1] << 16), (a[2] & 0xffffu) | (a[3] << 16),
                                 (bq[0] & 0xffffu) | (bq[1] << 16), (bq[2] & 0xffffu) | (bq[3] << 16) };
                    u32x4 lo = { (a[0] >> 16) | (a[1] & 0xffff0000u), (a[2] >> 16) | (a[3] & 0xffff0000u),
                                 (bq[0] >> 16) | (bq[1] & 0xffff0000u), (bq[2] >> 16) | (bq[3] & 0xffff0000u) };
                    *(u32x4*)(bhp + ks * 512) = hi;
                    *(u32x4*)(blp + ks * 512) = lo;
                }
            } else {
                const int jt = nw0 >> 6;
                u16* vp = Vf + (size_t)bh * 393216 + jt * 12288 + lane * 8;
                #pragma unroll
                for (int jkk = 0; jkk < 2; ++jkk) {
                    const int jk = ((nw0 >> 4) + jkk) & 3;
                    #pragma unroll
                    for (int dcf = 0; dcf < 6; ++dcf) {
                        unsigned int t[8];
                        #pragma unroll
                        for (int e = 0; e < 8; ++e)
                            t[e] = L[jkk * 16 + hf * 8 + e][dcf * 32 + l31];
                        u32x4 pk = { (t[0] & 0xffffu) | (t[1] << 16), (t[2] & 0xffffu) | (t[3] << 16),
                                     (t[4] & 0xffffu) | (t[5] << 16), (t[6] & 0xffffu) | (t[7] << 16) };
                        *(u32x4*)(vp + (jk * 6 + dcf) * 512) = pk;
                    }
                }
            }
        }
    }
}

// ---------------- K2: MFMA flash attention, 8 waves, j-split halves ----------
// grid (16 itile-groups, 16 bh), block 512: waves 0-3 = j[0,1024), 4-7 = j[1024,2048)
__global__ __launch_bounds__(512, 2) void attn_mfma(
    const u16* __restrict__ Qhi, const u16* __restrict__ Qlo,
    const u16* __restrict__ Khi, const u16* __restrict__ Klo,
    const u16* __restrict__ Vf, unsigned int* __restrict__ att2) {
    __shared__ __align__(16) u16 lds[2][36864];  // per half: K_hi | K_lo | V
    const int tid = threadIdx.x;
    const int lane = tid & 63;
    const int w = tid >> 6;
    const int half = w >> 2;
    const int wl = w & 3;
    const int hf = lane >> 5;
    const int bh = blockIdx.y;
    const int itq = blockIdx.x * 4 + wl;

    bf16x8 qh[12], ql[12];
    {
        size_t qb = (((size_t)bh * 64 + itq) * 12 * 64 + lane) * 8;
        #pragma unroll
        for (int ks = 0; ks < 12; ++ks) {
            qh[ks] = *(const bf16x8*)(Qhi + qb + ks * 512);
            ql[ks] = *(const bf16x8*)(Qlo + qb + ks * 512);
        }
    }

    const char* gK = (const char*)Khi + (size_t)bh * 786432 + (size_t)half * 393216;
    const char* gL = (const char*)Klo + (size_t)bh * 786432 + (size_t)half * 393216;
    const char* gV = (const char*)Vf  + (size_t)bh * 786432 + (size_t)half * 393216;
    const int soff = wl * 6144 + lane * 16;
    u16* ldsH = lds[half];

    u32x4 tr[18];
    #pragma unroll
    for (int cc = 0; cc < 6; ++cc) {
        tr[cc]      = *(const u32x4*)(gK + soff + cc * 1024);
        tr[6 + cc]  = *(const u32x4*)(gL + soff + cc * 1024);
        tr[12 + cc] = *(const u32x4*)(gV + soff + cc * 1024);
    }
    {
        char* lp = (char*)ldsH + soff;
        #pragma unroll
        for (int cc = 0; cc < 6; ++cc) {
            *(u32x4*)(lp + cc * 1024)         = tr[cc];
            *(u32x4*)(lp + 24576 + cc * 1024) = tr[6 + cc];
            *(u32x4*)(lp + 49152 + cc * 1024) = tr[12 + cc];
        }
    }
    __syncthreads();

    f32x16 o[6] = {};
    float m_run = -1e30f, l_run = 0.f;

    for (int jt = 0; jt < 16; ++jt) {
        f32x16 s00 = {}, s01 = {}, s10 = {}, s11 = {};
        #pragma unroll
        for (int mm = 0; mm < 6; ++mm) {
            const int k0 = mm * 2, k1 = mm * 2 + 1;
            bf16x8 kh00 = *(const bf16x8*)&ldsH[(size_t)((k0) * 64 + lane) * 8];
            bf16x8 kh01 = *(const bf16x8*)&ldsH[(size_t)((k1) * 64 + lane) * 8];
            bf16x8 kh10 = *(const bf16x8*)&ldsH[(size_t)((12 + k0) * 64 + lane) * 8];
            bf16x8 kh11 = *(const bf16x8*)&ldsH[(size_t)((12 + k1) * 64 + lane) * 8];
            bf16x8 kl00 = *(const bf16x8*)&ldsH[12288 + (size_t)((k0) * 64 + lane) * 8];
            bf16x8 kl01 = *(const bf16x8*)&ldsH[12288 + (size_t)((k1) * 64 + lane) * 8];
            bf16x8 kl10 = *(const bf16x8*)&ldsH[12288 + (size_t)((12 + k0) * 64 + lane) * 8];
            bf16x8 kl11 = *(const bf16x8*)&ldsH[12288 + (size_t)((12 + k1) * 64 + lane) * 8];
            s00 = MFMA(kh00, qh[k0], s00);
            s10 = MFMA(kh10, qh[k0], s10);
            s01 = MFMA(kh01, qh[k1], s01);
            s11 = MFMA(kh11, qh[k1], s11);
            s00 = MFMA(kh00, ql[k0], s00);
            s10 = MFMA(kh10, ql[k0], s10);
            s01 = MFMA(kh01, ql[k1], s01);
            s11 = MFMA(kh11, ql[k1], s11);
            s00 = MFMA(kl00, qh[k0], s00);
            s10 = MFMA(kl10, qh[k0], s10);
            s01 = MFMA(kl01, qh[k1], s01);
            s11 = MFMA(kl11, qh[k1], s11);
        }

        if (jt + 1 < 16) {
            const size_t joff = (size_t)(jt + 1) * 24576 + soff;
            #pragma unroll
            for (int cc = 0; cc < 6; ++cc) {
                tr[cc]      = *(const u32x4*)(gK + joff + cc * 1024);
                tr[6 + cc]  = *(const u32x4*)(gL + joff + cc * 1024);
                tr[12 + cc] = *(const u32x4*)(gV + joff + cc * 1024);
            }
        }

        f32x16 sj0 = s00 + s01;
        f32x16 sj1 = s10 + s11;
        float pm = -1e30f;
        #pragma unroll
        for (int r = 0; r < 16; ++r) pm = fmaxf(pm, fmaxf(sj0[r], sj1[r]));
        pm = fmaxf(pm, __shfl_xor(pm, 32, 64));
        if (!__all(pm <= m_run + 8.0f)) {   // T13 defer-rescale (log2 domain)
            float mnew = fmaxf(m_run, pm);
            float sc = exp2f(m_run - mnew);
            l_run *= sc;
            #pragma unroll
            for (int d = 0; d < 6; ++d) o[d] = o[d] * sc;
            m_run = mnew;
        }
        float rs = 0.f;
        #pragma unroll
        for (int r = 0; r < 16; ++r) {
            sj0[r] = exp2f(sj0[r] - m_run); rs += sj0[r];
            sj1[r] = exp2f(sj1[r] - m_run); rs += sj1[r];
        }
        rs += __shfl_xor(rs, 32, 64);
        l_run += rs;

        bf16x8 pf[4];
        {
            unsigned int pk[8], X[8];
            #pragma unroll
            for (int g = 0; g < 8; ++g) {
                pk[g] = pack2(sj0[2 * g], sj0[2 * g + 1]);
                X[g] = (unsigned int)__shfl_xor((int)pk[g], 32, 64);
            }
            u32x4 f0 = {hf ? X[2] : pk[0], hf ? X[3] : pk[1], hf ? pk[2] : X[0], hf ? pk[3] : X[1]};
            u32x4 f1 = {hf ? X[6] : pk[4], hf ? X[7] : pk[5], hf ? pk[6] : X[4], hf ? pk[7] : X[5]};
            pf[0] = __builtin_bit_cast(bf16x8, f0);
            pf[1] = __builtin_bit_cast(bf16x8, f1);
            #pragma unroll
            for (int g = 0; g < 8; ++g) {
                pk[g] = pack2(sj1[2 * g], sj1[2 * g + 1]);
                X[g] = (unsigned int)__shfl_xor((int)pk[g], 32, 64);
            }
            u32x4 f2 = {hf ? X[2] : pk[0], hf ? X[3] : pk[1], hf ? pk[2] : X[0], hf ? pk[3] : X[1]};
            u32x4 f3 = {hf ? X[6] : pk[4], hf ? X[7] : pk[5], hf ? pk[6] : X[4], hf ? pk[7] : X[5]};
            pf[2] = __builtin_bit_cast(bf16x8, f2);
            pf[3] = __builtin_bit_cast(bf16x8, f3);
        }

        #pragma unroll
        for (int jk = 0; jk < 4; ++jk)
            #pragma unroll
            for (int d = 0; d < 6; ++d) {
                bf16x8 vf = *(const bf16x8*)&ldsH[24576 + (size_t)((jk * 6 + d) * 64 + lane) * 8];
                o[d] = MFMA(vf, pf[jk], o[d]);
            }

        if (jt + 1 < 16) {
            __syncthreads();
            char* lp = (char*)ldsH + soff;
            #pragma unroll
            for (int cc = 0; cc < 6; ++cc) {
                *(u32x4*)(lp + cc * 1024)         = tr[cc];
                *(u32x4*)(lp + 24576 + cc * 1024) = tr[6 + cc];
                *(u32x4*)(lp + 49152 + cc * 1024) = tr[12 + cc];
            }
            __syncthreads();
        }
    }

    // ---- merge halves through LDS (frag-pattern, conflict-free) ----
    float* LM = (float*)&lds[0][0];
    __syncthreads();
    if (half == 1) {
        #pragma unroll
        for (int d = 0; d < 6; ++d)
            #pragma unroll
            for (int q = 0; q < 4; ++q) {
                f32x4v t = { o[d][4 * q], o[d][4 * q + 1], o[d][4 * q + 2], o[d][4 * q + 3] };
                *(f32x4v*)&LM[(((wl * 24 + d * 4 + q) * 64) + lane) * 4] = t;
            }
        LM[24576 + (wl * 64 + lane) * 2]     = m_run;
        LM[24576 + (wl * 64 + lane) * 2 + 1] = l_run;
    }
    __syncthreads();
    if (half == 0) {
        float mb = LM[24576 + (wl * 64 + lane) * 2];
        float lb = LM[24576 + (wl * 64 + lane) * 2 + 1];
        float mm = fmaxf(m_run, mb);
        float wa = exp2f(m_run - mm);
        float wb = exp2f(mb - mm);
        float inv = 1.0f / (l_run * wa + lb * wb);
        const int b2 = bh >> 3, hh = bh & 7;
        const int i31 = lane & 31;
        #pragma unroll
        for (int d = 0; d < 6; ++d)
            #pragma unroll
            for (int q = 0; q < 4; ++q) {
                f32x4v t = *(const f32x4v*)&LM[(((wl * 24 + d * 4 + q) * 64) + lane) * 4];
                #pragma unroll
                for (int j = 0; j < 4; ++j) {
                    int r = 4 * q + j;
                    float v = (o[d][r] * wa + t[j] * wb) * inv;
                    int dc = d * 32 + (r & 3) + 8 * (r >> 2) + 4 * hf;
                    int dd = dc / 3, cc = dc - dd * 3;
                    int hd = hh * 64 + dd;
                    int ks = hd >> 4, e = hd & 7;
                    int ln = i31 | (((hd >> 3) & 1) << 5);
                    size_t off = ((((size_t)(b2 * 3 + cc) * 32 + ks) * 64 + itq) * 512 + (size_t)ln * 8 + e);
                    att2[off] = splitpack(v);
                }
            }
    }
}

// ---------------- K3: output projection, MFMA split-bf16, no LDS ----------------
__global__ __launch_bounds__(256) void out_mfma(const unsigned int* __restrict__ att2,
                                                const float* __restrict__ wo,
                                                float* __restrict__ out) {
    const int tid = threadIdx.x, lane = tid & 63, w = tid >> 6, hf = lane >> 5, l31 = lane & 31;
    const int o0 = blockIdx.x * 32;
    const int n5 = blockIdx.y * 4 + w;
    const int b = blockIdx.z;
    const float* wp = wo + (size_t)(o0 + l31) * 512 + hf * 8;
    const unsigned int* ap = att2 + ((size_t)(b * 3) * 2048 + n5) * 512 + (size_t)lane * 8;
    f32x16 acc[3] = {};
    #pragma unroll 2
    for (int ks = 0; ks < 32; ++ks) {
        bf16x8 wh, wl;
        {
            f32x4v t0 = *(const f32x4v*)(wp + ks * 16);
            f32x4v t1 = *(const f32x4v*)(wp + ks * 16 + 4);
            #pragma unroll
            for (int e = 0; e < 4; ++e) {
                { float v = t0[e]; __bf16 hi = (__bf16)v; wh[e] = hi; wl[e] = (__bf16)(v - (float)hi); }
                { float v = t1[e]; __bf16 hi = (__bf16)v; wh[4 + e] = hi; wl[4 + e] = (__bf16)(v - (float)hi); }
            }
        }
        #pragma unroll
        for (int c = 0; c < 3; ++c) {
            const unsigned int* pc = ap + (size_t)c * 1048576 + ks * 32768;
            u32x4 a0 = *(const u32x4*)pc;
            u32x4 a1 = *(const u32x4*)(pc + 4);
            union { bf16x8 v; u32x4 u; } H, Lo;
            H.u  = { (a0[0] & 0xffffu) | (a0[1] << 16), (a0[2] & 0xffffu) | (a0[3] << 16),
                     (a1[0] & 0xffffu) | (a1[1] << 16), (a1[2] & 0xffffu) | (a1[3] << 16) };
            Lo.u = { (a0[0] >> 16) | (a0[1] & 0xffff0000u), (a0[2] >> 16) | (a0[3] & 0xffff0000u),
                     (a1[0] >> 16) | (a1[1] & 0xffff0000u), (a1[2] >> 16) | (a1[3] & 0xffff0000u) };
            acc[c] = MFMA(H.v, wh, acc[c]);
            acc[c] = MFMA(Lo.v, wh, acc[c]);
            acc[c] = MFMA(H.v, wl, acc[c]);
        }
    }
    #pragma unroll
    for (int r = 0; r < 16; ++r) {
        int n = (n5 << 5) + (r & 3) + 8 * (r >> 2) + 4 * hf;
        size_t off = ((size_t)(b * 2048 + n) * 256 + o0 + l31) * 3;
        out[off]     = acc[0][r];
        out[off + 1] = acc[1][r];
        out[off + 2] = acc[2][r];
    }
}

extern "C" void kernel_launch(void* const* d_in, const int* in_sizes, int n_in,
                              void* d_out, int out_size, void* d_ws, size_t ws_size,
                              hipStream_t stream) {
    const float* x     = (const float*)d_in[0];
    const float* w_qkv = (const float*)d_in[1];
    const float* w_out = (const float*)d_in[2];
    float* out = (float*)d_out;

    const size_t NB = (size_t)16 * 2048 * 192;
    u16* Qhi = (u16*)d_ws;
    u16* Qlo = Qhi + NB;
    u16* Khi = Qlo + NB;
    u16* Klo = Khi + NB;
    u16* Vf  = Klo + NB;
    unsigned int* att2 = (unsigned int*)(Vf + NB);

    qkv_mfma<<<dim3(24, 16, 2), 256, 0, stream>>>(x, w_qkv, Qhi, Qlo, Khi, Klo, Vf);
    attn_mfma<<<dim3(16, 16), 512, 0, stream>>>(Qhi, Qlo, Khi, Klo, Vf, att2);
    out_mfma<<<dim3(8, 16, 2), 256, 0, stream>>>(att2, w_out, out);
}

// Round 5
// 292.710 us; speedup vs baseline: 1.2685x; 1.2685x over previous
//
#include <hip/hip_runtime.h>
#include <hip/hip_bf16.h>

#define SCALE 0.07216878364870322f   // (3*64)^-0.5
#define LOG2E 1.4426950408889634f
// Q is pre-scaled by SCALE*LOG2E so attention logits are in log2 units.

typedef __bf16 bf16x8 __attribute__((ext_vector_type(8)));
typedef float f32x16 __attribute__((ext_vector_type(16)));
typedef float f32x4v __attribute__((ext_vector_type(4)));
typedef unsigned int u32x4 __attribute__((ext_vector_type(4)));
typedef unsigned short u16;

#define MFMA(a, b, c) __builtin_amdgcn_mfma_f32_32x32x16_bf16(a, b, c, 0, 0, 0)

__device__ __forceinline__ u16 b16(float v) { return __builtin_bit_cast(u16, (__bf16)v); }
__device__ __forceinline__ float fb16(u16 u) {
    unsigned int t = (unsigned int)u << 16;
    return __builtin_bit_cast(float, t);
}
__device__ __forceinline__ unsigned int splitpack(float v) {
    u16 h = b16(v);
    float r = v - fb16(h);
    return (unsigned int)h | ((unsigned int)b16(r) << 16);
}
__device__ __forceinline__ unsigned int pack2(float a, float b) {
    return (unsigned int)b16(a) | ((unsigned int)b16(b) << 16);
}

// ---------------- K1: QKV projection, MFMA split-bf16, zero-LDS main loop ----
__global__ __launch_bounds__(256) void qkv_mfma(const float* __restrict__ x,
                                                const float* __restrict__ wq,
                                                u16* __restrict__ Qhi, u16* __restrict__ Qlo,
                                                u16* __restrict__ Khi, u16* __restrict__ Klo,
                                                u16* __restrict__ Vf) {
    __shared__ unsigned int ldsr[2][32][196];
    const int tid = threadIdx.x;
    const int lane = tid & 63, w = tid >> 6, hf = lane >> 5, l31 = lane & 31;
    const int o0 = blockIdx.x * 64;
    const int n0 = blockIdx.y * 128;
    const int b = blockIdx.z;
    const int nw0 = n0 + w * 32;
    const int part = o0 >> 9;
    const int h = (o0 >> 6) & 7;
    const int bh = b * 8 + h;

    const float* xp = x + ((size_t)(b * 2048 + nw0 + l31)) * 768 + hf * 24;
    const float* wp0 = wq + (size_t)(o0 + l31) * 256 + hf * 8;
    const float* wp1 = wp0 + 32 * 256;

    f32x16 acc[3][2] = {};
    #pragma unroll 2
    for (int k0 = 0; k0 < 16; ++k0) {
        float xf[24], wf0[8], wf1[8];
        #pragma unroll
        for (int q = 0; q < 6; ++q) {
            f32x4v t = *(const f32x4v*)(xp + k0 * 48 + q * 4);
            xf[q * 4 + 0] = t[0]; xf[q * 4 + 1] = t[1];
            xf[q * 4 + 2] = t[2]; xf[q * 4 + 3] = t[3];
        }
        {
            f32x4v t0 = *(const f32x4v*)(wp0 + k0 * 16);
            f32x4v t1 = *(const f32x4v*)(wp0 + k0 * 16 + 4);
            f32x4v t2 = *(const f32x4v*)(wp1 + k0 * 16);
            f32x4v t3 = *(const f32x4v*)(wp1 + k0 * 16 + 4);
            #pragma unroll
            for (int e = 0; e < 4; ++e) {
                wf0[e] = t0[e]; wf0[4 + e] = t1[e];
                wf1[e] = t2[e]; wf1[4 + e] = t3[e];
            }
        }
        bf16x8 xh[3], xl[3], wh[2], wl[2];
        #pragma unroll
        for (int c = 0; c < 3; ++c)
            #pragma unroll
            for (int e = 0; e < 8; ++e) {
                float v = xf[e * 3 + c];
                __bf16 hi = (__bf16)v;
                xh[c][e] = hi;
                xl[c][e] = (__bf16)(v - (float)hi);
            }
        #pragma unroll
        for (int e = 0; e < 8; ++e) {
            { float v = wf0[e]; __bf16 hi = (__bf16)v; wh[0][e] = hi; wl[0][e] = (__bf16)(v - (float)hi); }
            { float v = wf1[e]; __bf16 hi = (__bf16)v; wh[1][e] = hi; wl[1][e] = (__bf16)(v - (float)hi); }
        }
        #pragma unroll
        for (int c = 0; c < 3; ++c)
            #pragma unroll
            for (int ot = 0; ot < 2; ++ot) {
                acc[c][ot] = MFMA(xh[c], wh[ot], acc[c][ot]);
                acc[c][ot] = MFMA(xl[c], wh[ot], acc[c][ot]);
                acc[c][ot] = MFMA(xh[c], wl[ot], acc[c][ot]);
            }
    }

    #pragma unroll
    for (int round = 0; round < 2; ++round) {
        __syncthreads();
        if ((w >> 1) == round) {
            unsigned int (*L)[196] = ldsr[w & 1];
            #pragma unroll
            for (int c = 0; c < 3; ++c)
                #pragma unroll
                for (int ot = 0; ot < 2; ++ot)
                    #pragma unroll
                    for (int r = 0; r < 16; ++r) {
                        float v = acc[c][ot][r];
                        if (part == 0) v *= (SCALE * LOG2E);
                        int nn = (r & 3) + 8 * (r >> 2) + 4 * hf;
                        int dcol = 3 * (ot * 32 + l31) + c;
                        L[nn][dcol] = (part == 2) ? (unsigned int)b16(v) : splitpack(v);
                    }
            if (part < 2) {
                const int itqw = blockIdx.y * 4 + w;
                u16* bhp = (part == 0 ? Qhi : Khi) + (size_t)bh * 393216 + itqw * 6144 + lane * 8;
                u16* blp = (part == 0 ? Qlo : Klo) + (size_t)bh * 393216 + itqw * 6144 + lane * 8;
                #pragma unroll
                for (int ks = 0; ks < 12; ++ks) {
                    const unsigned int* p = &L[l31][ks * 16 + hf * 8];
                    u32x4 a = *(const u32x4*)p;
                    u32x4 bq = *(const u32x4*)(p + 4);
                    u32x4 hi = { (a[0] & 0xffffu) | (a[1] << 16), (a[2] & 0xffffu) | (a[3] << 16),
                                 (bq[0] & 0xffffu) | (bq[1] << 16), (bq[2] & 0xffffu) | (bq[3] << 16) };
                    u32x4 lo = { (a[0] >> 16) | (a[1] & 0xffff0000u), (a[2] >> 16) | (a[3] & 0xffff0000u),
                                 (bq[0] >> 16) | (bq[1] & 0xffff0000u), (bq[2] >> 16) | (bq[3] & 0xffff0000u) };
                    *(u32x4*)(bhp + ks * 512) = hi;
                    *(u32x4*)(blp + ks * 512) = lo;
                }
            } else {
                const int jt = nw0 >> 6;
                u16* vp = Vf + (size_t)bh * 393216 + jt * 12288 + lane * 8;
                #pragma unroll
                for (int jkk = 0; jkk < 2; ++jkk) {
                    const int jk = ((nw0 >> 4) + jkk) & 3;
                    #pragma unroll
                    for (int dcf = 0; dcf < 6; ++dcf) {
                        unsigned int t[8];
                        #pragma unroll
                        for (int e = 0; e < 8; ++e)
                            t[e] = L[jkk * 16 + hf * 8 + e][dcf * 32 + l31];
                        u32x4 pk = { (t[0] & 0xffffu) | (t[1] << 16), (t[2] & 0xffffu) | (t[3] << 16),
                                     (t[4] & 0xffffu) | (t[5] << 16), (t[6] & 0xffffu) | (t[7] << 16) };
                        *(u32x4*)(vp + (jk * 6 + dcf) * 512) = pk;
                    }
                }
            }
        }
    }
}

// ---------------- K2: MFMA flash attention, j-split across blocks ------------
// grid (16 itile-groups, 16 bh, 2 j-halves), block 256 (4 waves; wave = one 32-row i-group)
// Writes unnormalized partial O (bf16) + (m,l) per half; combined by attn_combine.
__global__ __launch_bounds__(256, 2) void attn_mfma(
    const u16* __restrict__ Qhi, const u16* __restrict__ Qlo,
    const u16* __restrict__ Khi, const u16* __restrict__ Klo,
    const u16* __restrict__ Vf, u16* __restrict__ Opart, float* __restrict__ MLp) {
    __shared__ __align__(16) u16 lds[36864];  // K_hi | K_lo | V
    const int tid = threadIdx.x;
    const int lane = tid & 63;
    const int w = tid >> 6;
    const int hf = lane >> 5;
    const int bh = blockIdx.y;
    const int half = blockIdx.z;
    const int itq = blockIdx.x * 4 + w;

    bf16x8 qh[12], ql[12];
    {
        size_t qb = (((size_t)bh * 64 + itq) * 12 * 64 + lane) * 8;
        #pragma unroll
        for (int ks = 0; ks < 12; ++ks) {
            qh[ks] = *(const bf16x8*)(Qhi + qb + ks * 512);
            ql[ks] = *(const bf16x8*)(Qlo + qb + ks * 512);
        }
    }

    const char* gK = (const char*)Khi + (size_t)bh * 786432 + (size_t)half * 393216;
    const char* gL = (const char*)Klo + (size_t)bh * 786432 + (size_t)half * 393216;
    const char* gV = (const char*)Vf  + (size_t)bh * 786432 + (size_t)half * 393216;
    const int soff = w * 6144 + lane * 16;

    u32x4 tr[18];
    #pragma unroll
    for (int cc = 0; cc < 6; ++cc) {
        tr[cc]      = *(const u32x4*)(gK + soff + cc * 1024);
        tr[6 + cc]  = *(const u32x4*)(gL + soff + cc * 1024);
        tr[12 + cc] = *(const u32x4*)(gV + soff + cc * 1024);
    }
    {
        char* lp = (char*)lds + soff;
        #pragma unroll
        for (int cc = 0; cc < 6; ++cc) {
            *(u32x4*)(lp + cc * 1024)         = tr[cc];
            *(u32x4*)(lp + 24576 + cc * 1024) = tr[6 + cc];
            *(u32x4*)(lp + 49152 + cc * 1024) = tr[12 + cc];
        }
    }
    __syncthreads();

    f32x16 o[6] = {};
    float m_run = -1e30f, l_run = 0.f;

    for (int jt = 0; jt < 16; ++jt) {
        f32x16 s00 = {}, s01 = {}, s10 = {}, s11 = {};
        #pragma unroll
        for (int mm = 0; mm < 6; ++mm) {
            const int k0 = mm * 2, k1 = mm * 2 + 1;
            bf16x8 kh00 = *(const bf16x8*)&lds[(size_t)((k0) * 64 + lane) * 8];
            bf16x8 kh01 = *(const bf16x8*)&lds[(size_t)((k1) * 64 + lane) * 8];
            bf16x8 kh10 = *(const bf16x8*)&lds[(size_t)((12 + k0) * 64 + lane) * 8];
            bf16x8 kh11 = *(const bf16x8*)&lds[(size_t)((12 + k1) * 64 + lane) * 8];
            bf16x8 kl00 = *(const bf16x8*)&lds[12288 + (size_t)((k0) * 64 + lane) * 8];
            bf16x8 kl01 = *(const bf16x8*)&lds[12288 + (size_t)((k1) * 64 + lane) * 8];
            bf16x8 kl10 = *(const bf16x8*)&lds[12288 + (size_t)((12 + k0) * 64 + lane) * 8];
            bf16x8 kl11 = *(const bf16x8*)&lds[12288 + (size_t)((12 + k1) * 64 + lane) * 8];
            s00 = MFMA(kh00, qh[k0], s00);
            s10 = MFMA(kh10, qh[k0], s10);
            s01 = MFMA(kh01, qh[k1], s01);
            s11 = MFMA(kh11, qh[k1], s11);
            s00 = MFMA(kh00, ql[k0], s00);
            s10 = MFMA(kh10, ql[k0], s10);
            s01 = MFMA(kh01, ql[k1], s01);
            s11 = MFMA(kh11, ql[k1], s11);
            s00 = MFMA(kl00, qh[k0], s00);
            s10 = MFMA(kl10, qh[k0], s10);
            s01 = MFMA(kl01, qh[k1], s01);
            s11 = MFMA(kl11, qh[k1], s11);
        }

        if (jt + 1 < 16) {
            const size_t joff = (size_t)(jt + 1) * 24576 + soff;
            #pragma unroll
            for (int cc = 0; cc < 6; ++cc) {
                tr[cc]      = *(const u32x4*)(gK + joff + cc * 1024);
                tr[6 + cc]  = *(const u32x4*)(gL + joff + cc * 1024);
                tr[12 + cc] = *(const u32x4*)(gV + joff + cc * 1024);
            }
        }

        f32x16 sj0 = s00 + s01;
        f32x16 sj1 = s10 + s11;
        float pm = -1e30f;
        #pragma unroll
        for (int r = 0; r < 16; ++r) pm = fmaxf(pm, fmaxf(sj0[r], sj1[r]));
        pm = fmaxf(pm, __shfl_xor(pm, 32, 64));
        if (!__all(pm <= m_run + 8.0f)) {   // T13 defer-rescale (log2 domain)
            float mnew = fmaxf(m_run, pm);
            float sc = exp2f(m_run - mnew);
            l_run *= sc;
            #pragma unroll
            for (int d = 0; d < 6; ++d) o[d] = o[d] * sc;
            m_run = mnew;
        }
        float rs = 0.f;
        #pragma unroll
        for (int r = 0; r < 16; ++r) {
            sj0[r] = exp2f(sj0[r] - m_run); rs += sj0[r];
            sj1[r] = exp2f(sj1[r] - m_run); rs += sj1[r];
        }
        rs += __shfl_xor(rs, 32, 64);
        l_run += rs;

        bf16x8 pf[4];
        {
            unsigned int pk[8], X[8];
            #pragma unroll
            for (int g = 0; g < 8; ++g) {
                pk[g] = pack2(sj0[2 * g], sj0[2 * g + 1]);
                X[g] = (unsigned int)__shfl_xor((int)pk[g], 32, 64);
            }
            u32x4 f0 = {hf ? X[2] : pk[0], hf ? X[3] : pk[1], hf ? pk[2] : X[0], hf ? pk[3] : X[1]};
            u32x4 f1 = {hf ? X[6] : pk[4], hf ? X[7] : pk[5], hf ? pk[6] : X[4], hf ? pk[7] : X[5]};
            pf[0] = __builtin_bit_cast(bf16x8, f0);
            pf[1] = __builtin_bit_cast(bf16x8, f1);
            #pragma unroll
            for (int g = 0; g < 8; ++g) {
                pk[g] = pack2(sj1[2 * g], sj1[2 * g + 1]);
                X[g] = (unsigned int)__shfl_xor((int)pk[g], 32, 64);
            }
            u32x4 f2 = {hf ? X[2] : pk[0], hf ? X[3] : pk[1], hf ? pk[2] : X[0], hf ? pk[3] : X[1]};
            u32x4 f3 = {hf ? X[6] : pk[4], hf ? X[7] : pk[5], hf ? pk[6] : X[4], hf ? pk[7] : X[5]};
            pf[2] = __builtin_bit_cast(bf16x8, f2);
            pf[3] = __builtin_bit_cast(bf16x8, f3);
        }

        #pragma unroll
        for (int jk = 0; jk < 4; ++jk)
            #pragma unroll
            for (int d = 0; d < 6; ++d) {
                bf16x8 vf = *(const bf16x8*)&lds[24576 + (size_t)((jk * 6 + d) * 64 + lane) * 8];
                o[d] = MFMA(vf, pf[jk], o[d]);
            }

        if (jt + 1 < 16) {
            __syncthreads();
            char* lp = (char*)lds + soff;
            #pragma unroll
            for (int cc = 0; cc < 6; ++cc) {
                *(u32x4*)(lp + cc * 1024)         = tr[cc];
                *(u32x4*)(lp + 24576 + cc * 1024) = tr[6 + cc];
                *(u32x4*)(lp + 49152 + cc * 1024) = tr[12 + cc];
            }
            __syncthreads();
        }
    }

    // ---- epilogue: write unnormalized bf16 partial O + (m,l) ----
    const int tI = bh * 64 + itq;
    u16* Op = Opart + ((size_t)(half * 1024 + tI) * 96) * 64 + lane;
    #pragma unroll
    for (int d = 0; d < 6; ++d)
        #pragma unroll
        for (int r = 0; r < 16; ++r)
            Op[(d * 16 + r) * 64] = b16(o[d][r]);
    float* mlp = MLp + (size_t)(half * 1024 + tI) * 128 + lane * 2;
    mlp[0] = m_run;
    mlp[1] = l_run;
}

// ---------------- K2b: combine j-halves -> att2 (split-pack frag layout) -----
// grid 256 blocks x 256 threads; wave handles one (bh,itq) tile
__global__ __launch_bounds__(256) void attn_combine(const u16* __restrict__ Opart,
                                                    const float* __restrict__ MLp,
                                                    unsigned int* __restrict__ att2) {
    const int tid = threadIdx.x, lane = tid & 63, w = tid >> 6, hf = lane >> 5;
    const int tI = blockIdx.x * 4 + w;     // 0..1023
    const int bh = tI >> 6, itq = tI & 63;
    const float* mla = MLp + (size_t)tI * 128 + lane * 2;
    const float* mlb = MLp + (size_t)(1024 + tI) * 128 + lane * 2;
    float ma = mla[0], la = mla[1];
    float mb = mlb[0], lb = mlb[1];
    float mm = fmaxf(ma, mb);
    float wa = exp2f(ma - mm), wb = exp2f(mb - mm);
    float inv = 1.0f / (la * wa + lb * wb);
    const u16* Oa = Opart + ((size_t)tI * 96) * 64 + lane;
    const u16* Ob = Opart + ((size_t)(1024 + tI) * 96) * 64 + lane;
    const int b2 = bh >> 3, hh = bh & 7;
    const int i31 = lane & 31;
    #pragma unroll
    for (int d = 0; d < 6; ++d)
        #pragma unroll
        for (int r = 0; r < 16; ++r) {
            float va = fb16(Oa[(d * 16 + r) * 64]);
            float vb = fb16(Ob[(d * 16 + r) * 64]);
            float v = (va * wa + vb * wb) * inv;
            int dc = d * 32 + (r & 3) + 8 * (r >> 2) + 4 * hf;
            int dd = dc / 3, cc = dc - dd * 3;
            int hd = hh * 64 + dd;
            int ks = hd >> 4, e = hd & 7;
            int ln = i31 | (((hd >> 3) & 1) << 5);
            size_t off = ((((size_t)(b2 * 3 + cc) * 32 + ks) * 64 + itq) * 512 + (size_t)ln * 8 + e);
            att2[off] = splitpack(v);
        }
}

// ---------------- K3: output projection, MFMA split-bf16, no LDS ----------------
__global__ __launch_bounds__(256) void out_mfma(const unsigned int* __restrict__ att2,
                                                const float* __restrict__ wo,
                                                float* __restrict__ out) {
    const int tid = threadIdx.x, lane = tid & 63, w = tid >> 6, hf = lane >> 5, l31 = lane & 31;
    const int o0 = blockIdx.x * 32;
    const int n5 = blockIdx.y * 4 + w;
    const int b = blockIdx.z;
    const float* wp = wo + (size_t)(o0 + l31) * 512 + hf * 8;
    const unsigned int* ap = att2 + ((size_t)(b * 3) * 2048 + n5) * 512 + (size_t)lane * 8;
    f32x16 acc[3] = {};
    #pragma unroll 2
    for (int ks = 0; ks < 32; ++ks) {
        bf16x8 wh, wl;
        {
            f32x4v t0 = *(const f32x4v*)(wp + ks * 16);
            f32x4v t1 = *(const f32x4v*)(wp + ks * 16 + 4);
            #pragma unroll
            for (int e = 0; e < 4; ++e) {
                { float v = t0[e]; __bf16 hi = (__bf16)v; wh[e] = hi; wl[e] = (__bf16)(v - (float)hi); }
                { float v = t1[e]; __bf16 hi = (__bf16)v; wh[4 + e] = hi; wl[4 + e] = (__bf16)(v - (float)hi); }
            }
        }
        #pragma unroll
        for (int c = 0; c < 3; ++c) {
            const unsigned int* pc = ap + (size_t)c * 1048576 + ks * 32768;
            u32x4 a0 = *(const u32x4*)pc;
            u32x4 a1 = *(const u32x4*)(pc + 4);
            union { bf16x8 v; u32x4 u; } H, Lo;
            H.u  = { (a0[0] & 0xffffu) | (a0[1] << 16), (a0[2] & 0xffffu) | (a0[3] << 16),
                     (a1[0] & 0xffffu) | (a1[1] << 16), (a1[2] & 0xffffu) | (a1[3] << 16) };
            Lo.u = { (a0[0] >> 16) | (a0[1] & 0xffff0000u), (a0[2] >> 16) | (a0[3] & 0xffff0000u),
                     (a1[0] >> 16) | (a1[1] & 0xffff0000u), (a1[2] >> 16) | (a1[3] & 0xffff0000u) };
            acc[c] = MFMA(H.v, wh, acc[c]);
            acc[c] = MFMA(Lo.v, wh, acc[c]);
            acc[c] = MFMA(H.v, wl, acc[c]);
        }
    }
    #pragma unroll
    for (int r = 0; r < 16; ++r) {
        int n = (n5 << 5) + (r & 3) + 8 * (r >> 2) + 4 * hf;
        size_t off = ((size_t)(b * 2048 + n) * 256 + o0 + l31) * 3;
        out[off]     = acc[0][r];
        out[off + 1] = acc[1][r];
        out[off + 2] = acc[2][r];
    }
}

extern "C" void kernel_launch(void* const* d_in, const int* in_sizes, int n_in,
                              void* d_out, int out_size, void* d_ws, size_t ws_size,
                              hipStream_t stream) {
    const float* x     = (const float*)d_in[0];
    const float* w_qkv = (const float*)d_in[1];
    const float* w_out = (const float*)d_in[2];
    float* out = (float*)d_out;

    const size_t NB = (size_t)16 * 2048 * 192;  // 6.29M elems
    u16* Qhi = (u16*)d_ws;
    u16* Qlo = Qhi + NB;
    u16* Khi = Qlo + NB;
    u16* Klo = Khi + NB;
    u16* Vf  = Klo + NB;
    u16* Opart = Vf + NB;                       // 2*NB u16 = 25.2MB
    float* MLp = (float*)(Opart + 2 * NB);      // 262144 floats = 1MB
    unsigned int* att2 = (unsigned int*)Qhi;    // reuses Qhi+Qlo (dead after attn)

    qkv_mfma<<<dim3(24, 16, 2), 256, 0, stream>>>(x, w_qkv, Qhi, Qlo, Khi, Klo, Vf);
    attn_mfma<<<dim3(16, 16, 2), 256, 0, stream>>>(Qhi, Qlo, Khi, Klo, Vf, Opart, MLp);
    attn_combine<<<dim3(256), 256, 0, stream>>>(Opart, MLp, att2);
    out_mfma<<<dim3(8, 16, 2), 256, 0, stream>>>(att2, w_out, out);
}

// Round 6
// 270.565 us; speedup vs baseline: 1.3723x; 1.0818x over previous
//
#include <hip/hip_runtime.h>
#include <hip/hip_bf16.h>

#define SCALE 0.07216878364870322f   // (3*64)^-0.5
#define LOG2E 1.4426950408889634f
// Q is pre-scaled by SCALE*LOG2E so attention logits are in log2 units.

typedef __bf16 bf16x8 __attribute__((ext_vector_type(8)));
typedef float f32x16 __attribute__((ext_vector_type(16)));
typedef float f32x4v __attribute__((ext_vector_type(4)));
typedef unsigned int u32x4 __attribute__((ext_vector_type(4)));
typedef unsigned short u16;

#define MFMA(a, b, c) __builtin_amdgcn_mfma_f32_32x32x16_bf16(a, b, c, 0, 0, 0)

__device__ __forceinline__ u16 b16(float v) { return __builtin_bit_cast(u16, (__bf16)v); }
__device__ __forceinline__ float fb16(u16 u) {
    unsigned int t = (unsigned int)u << 16;
    return __builtin_bit_cast(float, t);
}
__device__ __forceinline__ unsigned int splitpack(float v) {
    u16 h = b16(v);
    float r = v - fb16(h);
    return (unsigned int)h | ((unsigned int)b16(r) << 16);
}
__device__ __forceinline__ unsigned int pack2(float a, float b) {
    return (unsigned int)b16(a) | ((unsigned int)b16(b) << 16);
}

// ---------------- K1: QKV projection, MFMA split-bf16, zero-LDS main loop ----
__global__ __launch_bounds__(256) void qkv_mfma(const float* __restrict__ x,
                                                const float* __restrict__ wq,
                                                u16* __restrict__ Qhi, u16* __restrict__ Qlo,
                                                u16* __restrict__ Khi, u16* __restrict__ Klo,
                                                u16* __restrict__ Vf) {
    __shared__ unsigned int ldsr[2][32][196];
    const int tid = threadIdx.x;
    const int lane = tid & 63, w = tid >> 6, hf = lane >> 5, l31 = lane & 31;
    const int o0 = blockIdx.x * 64;
    const int n0 = blockIdx.y * 128;
    const int b = blockIdx.z;
    const int nw0 = n0 + w * 32;
    const int part = o0 >> 9;
    const int h = (o0 >> 6) & 7;
    const int bh = b * 8 + h;

    const float* xp = x + ((size_t)(b * 2048 + nw0 + l31)) * 768 + hf * 24;
    const float* wp0 = wq + (size_t)(o0 + l31) * 256 + hf * 8;
    const float* wp1 = wp0 + 32 * 256;

    f32x16 acc[3][2] = {};
    #pragma unroll 2
    for (int k0 = 0; k0 < 16; ++k0) {
        float xf[24], wf0[8], wf1[8];
        #pragma unroll
        for (int q = 0; q < 6; ++q) {
            f32x4v t = *(const f32x4v*)(xp + k0 * 48 + q * 4);
            xf[q * 4 + 0] = t[0]; xf[q * 4 + 1] = t[1];
            xf[q * 4 + 2] = t[2]; xf[q * 4 + 3] = t[3];
        }
        {
            f32x4v t0 = *(const f32x4v*)(wp0 + k0 * 16);
            f32x4v t1 = *(const f32x4v*)(wp0 + k0 * 16 + 4);
            f32x4v t2 = *(const f32x4v*)(wp1 + k0 * 16);
            f32x4v t3 = *(const f32x4v*)(wp1 + k0 * 16 + 4);
            #pragma unroll
            for (int e = 0; e < 4; ++e) {
                wf0[e] = t0[e]; wf0[4 + e] = t1[e];
                wf1[e] = t2[e]; wf1[4 + e] = t3[e];
            }
        }
        bf16x8 xh[3], xl[3], wh[2], wl[2];
        #pragma unroll
        for (int c = 0; c < 3; ++c)
            #pragma unroll
            for (int e = 0; e < 8; ++e) {
                float v = xf[e * 3 + c];
                __bf16 hi = (__bf16)v;
                xh[c][e] = hi;
                xl[c][e] = (__bf16)(v - (float)hi);
            }
        #pragma unroll
        for (int e = 0; e < 8; ++e) {
            { float v = wf0[e]; __bf16 hi = (__bf16)v; wh[0][e] = hi; wl[0][e] = (__bf16)(v - (float)hi); }
            { float v = wf1[e]; __bf16 hi = (__bf16)v; wh[1][e] = hi; wl[1][e] = (__bf16)(v - (float)hi); }
        }
        #pragma unroll
        for (int c = 0; c < 3; ++c)
            #pragma unroll
            for (int ot = 0; ot < 2; ++ot) {
                acc[c][ot] = MFMA(xh[c], wh[ot], acc[c][ot]);
                acc[c][ot] = MFMA(xl[c], wh[ot], acc[c][ot]);
                acc[c][ot] = MFMA(xh[c], wl[ot], acc[c][ot]);
            }
    }

    #pragma unroll
    for (int round = 0; round < 2; ++round) {
        __syncthreads();
        if ((w >> 1) == round) {
            unsigned int (*L)[196] = ldsr[w & 1];
            #pragma unroll
            for (int c = 0; c < 3; ++c)
                #pragma unroll
                for (int ot = 0; ot < 2; ++ot)
                    #pragma unroll
                    for (int r = 0; r < 16; ++r) {
                        float v = acc[c][ot][r];
                        if (part == 0) v *= (SCALE * LOG2E);
                        int nn = (r & 3) + 8 * (r >> 2) + 4 * hf;
                        int dcol = 3 * (ot * 32 + l31) + c;
                        L[nn][dcol] = (part == 2) ? (unsigned int)b16(v) : splitpack(v);
                    }
            if (part < 2) {
                const int itqw = blockIdx.y * 4 + w;
                u16* bhp = (part == 0 ? Qhi : Khi) + (size_t)bh * 393216 + itqw * 6144 + lane * 8;
                u16* blp = (part == 0 ? Qlo : Klo) + (size_t)bh * 393216 + itqw * 6144 + lane * 8;
                #pragma unroll
                for (int ks = 0; ks < 12; ++ks) {
                    const unsigned int* p = &L[l31][ks * 16 + hf * 8];
                    u32x4 a = *(const u32x4*)p;
                    u32x4 bq = *(const u32x4*)(p + 4);
                    u32x4 hi = { (a[0] & 0xffffu) | (a[1] << 16), (a[2] & 0xffffu) | (a[3] << 16),
                                 (bq[0] & 0xffffu) | (bq[1] << 16), (bq[2] & 0xffffu) | (bq[3] << 16) };
                    u32x4 lo = { (a[0] >> 16) | (a[1] & 0xffff0000u), (a[2] >> 16) | (a[3] & 0xffff0000u),
                                 (bq[0] >> 16) | (bq[1] & 0xffff0000u), (bq[2] >> 16) | (bq[3] & 0xffff0000u) };
                    *(u32x4*)(bhp + ks * 512) = hi;
                    *(u32x4*)(blp + ks * 512) = lo;
                }
            } else {
                const int jt = nw0 >> 6;
                u16* vp = Vf + (size_t)bh * 393216 + jt * 12288 + lane * 8;
                #pragma unroll
                for (int jkk = 0; jkk < 2; ++jkk) {
                    const int jk = ((nw0 >> 4) + jkk) & 3;
                    #pragma unroll
                    for (int dcf = 0; dcf < 6; ++dcf) {
                        unsigned int t[8];
                        #pragma unroll
                        for (int e = 0; e < 8; ++e)
                            t[e] = L[jkk * 16 + hf * 8 + e][dcf * 32 + l31];
                        u32x4 pk = { (t[0] & 0xffffu) | (t[1] << 16), (t[2] & 0xffffu) | (t[3] << 16),
                                     (t[4] & 0xffffu) | (t[5] << 16), (t[6] & 0xffffu) | (t[7] << 16) };
                        *(u32x4*)(vp + (jk * 6 + dcf) * 512) = pk;
                    }
                }
            }
        }
    }
}

// ---------------- K2: MFMA flash attention, j-split across blocks ------------
// grid 512 (flattened, XCD-swizzled), block 256 (4 waves; wave = one 32-row i-group)
// Swizzle: all 16 blocks sharing one (bh,half) K/V slab land on the same XCD.
__global__ __launch_bounds__(256, 1) void attn_mfma(
    const u16* __restrict__ Qhi, const u16* __restrict__ Qlo,
    const u16* __restrict__ Khi, const u16* __restrict__ Klo,
    const u16* __restrict__ Vf, u16* __restrict__ Opart, float* __restrict__ MLp) {
    __shared__ __align__(16) u16 lds[36864];  // K_hi | K_lo | V
    const int tid = threadIdx.x;
    const int lane = tid & 63;
    const int w = tid >> 6;
    const int hf = lane >> 5;
    // XCD-aware decode: id%8 picks XCD; group g = (bh,half) is constant per XCD chunk.
    const int id = blockIdx.x;                     // 0..511
    const int rem = id >> 3;                       // 0..63
    const int g = ((rem >> 4) << 3) | (id & 7);    // 0..31: (bh,half) group
    const int i16 = rem & 15;                      // 0..15: i-tile group
    const int bh = g >> 1;
    const int half = g & 1;
    const int itq = i16 * 4 + w;

    bf16x8 qh[12], ql[12];
    {
        size_t qb = (((size_t)bh * 64 + itq) * 12 * 64 + lane) * 8;
        #pragma unroll
        for (int ks = 0; ks < 12; ++ks) {
            qh[ks] = *(const bf16x8*)(Qhi + qb + ks * 512);
            ql[ks] = *(const bf16x8*)(Qlo + qb + ks * 512);
        }
    }

    const char* gK = (const char*)Khi + (size_t)bh * 786432 + (size_t)half * 393216;
    const char* gL = (const char*)Klo + (size_t)bh * 786432 + (size_t)half * 393216;
    const char* gV = (const char*)Vf  + (size_t)bh * 786432 + (size_t)half * 393216;
    const int soff = w * 6144 + lane * 16;

    u32x4 tr[18];
    #pragma unroll
    for (int cc = 0; cc < 6; ++cc) {
        tr[cc]      = *(const u32x4*)(gK + soff + cc * 1024);
        tr[6 + cc]  = *(const u32x4*)(gL + soff + cc * 1024);
        tr[12 + cc] = *(const u32x4*)(gV + soff + cc * 1024);
    }
    {
        char* lp = (char*)lds + soff;
        #pragma unroll
        for (int cc = 0; cc < 6; ++cc) {
            *(u32x4*)(lp + cc * 1024)         = tr[cc];
            *(u32x4*)(lp + 24576 + cc * 1024) = tr[6 + cc];
            *(u32x4*)(lp + 49152 + cc * 1024) = tr[12 + cc];
        }
    }
    __syncthreads();

    f32x16 o[6] = {};
    float m_run = -1e30f, l_run = 0.f;

    for (int jt = 0; jt < 16; ++jt) {
        f32x16 s00 = {}, s01 = {}, s10 = {}, s11 = {};
        #pragma unroll
        for (int mm = 0; mm < 6; ++mm) {
            const int k0 = mm * 2, k1 = mm * 2 + 1;
            bf16x8 kh00 = *(const bf16x8*)&lds[(size_t)((k0) * 64 + lane) * 8];
            bf16x8 kh01 = *(const bf16x8*)&lds[(size_t)((k1) * 64 + lane) * 8];
            bf16x8 kh10 = *(const bf16x8*)&lds[(size_t)((12 + k0) * 64 + lane) * 8];
            bf16x8 kh11 = *(const bf16x8*)&lds[(size_t)((12 + k1) * 64 + lane) * 8];
            bf16x8 kl00 = *(const bf16x8*)&lds[12288 + (size_t)((k0) * 64 + lane) * 8];
            bf16x8 kl01 = *(const bf16x8*)&lds[12288 + (size_t)((k1) * 64 + lane) * 8];
            bf16x8 kl10 = *(const bf16x8*)&lds[12288 + (size_t)((12 + k0) * 64 + lane) * 8];
            bf16x8 kl11 = *(const bf16x8*)&lds[12288 + (size_t)((12 + k1) * 64 + lane) * 8];
            s00 = MFMA(kh00, qh[k0], s00);
            s10 = MFMA(kh10, qh[k0], s10);
            s01 = MFMA(kh01, qh[k1], s01);
            s11 = MFMA(kh11, qh[k1], s11);
            s00 = MFMA(kh00, ql[k0], s00);
            s10 = MFMA(kh10, ql[k0], s10);
            s01 = MFMA(kh01, ql[k1], s01);
            s11 = MFMA(kh11, ql[k1], s11);
            s00 = MFMA(kl00, qh[k0], s00);
            s10 = MFMA(kl10, qh[k0], s10);
            s01 = MFMA(kl01, qh[k1], s01);
            s11 = MFMA(kl11, qh[k1], s11);
        }

        if (jt + 1 < 16) {
            const size_t joff = (size_t)(jt + 1) * 24576 + soff;
            #pragma unroll
            for (int cc = 0; cc < 6; ++cc) {
                tr[cc]      = *(const u32x4*)(gK + joff + cc * 1024);
                tr[6 + cc]  = *(const u32x4*)(gL + joff + cc * 1024);
                tr[12 + cc] = *(const u32x4*)(gV + joff + cc * 1024);
            }
        }

        f32x16 sj0 = s00 + s01;
        f32x16 sj1 = s10 + s11;
        float pm = -1e30f;
        #pragma unroll
        for (int r = 0; r < 16; ++r) pm = fmaxf(pm, fmaxf(sj0[r], sj1[r]));
        pm = fmaxf(pm, __shfl_xor(pm, 32, 64));
        if (!__all(pm <= m_run + 8.0f)) {   // T13 defer-rescale (log2 domain)
            float mnew = fmaxf(m_run, pm);
            float sc = exp2f(m_run - mnew);
            l_run *= sc;
            #pragma unroll
            for (int d = 0; d < 6; ++d) o[d] = o[d] * sc;
            m_run = mnew;
        }
        float rs = 0.f;
        #pragma unroll
        for (int r = 0; r < 16; ++r) {
            sj0[r] = exp2f(sj0[r] - m_run); rs += sj0[r];
            sj1[r] = exp2f(sj1[r] - m_run); rs += sj1[r];
        }
        rs += __shfl_xor(rs, 32, 64);
        l_run += rs;

        bf16x8 pf[4];
        {
            unsigned int pk[8], X[8];
            #pragma unroll
            for (int g2 = 0; g2 < 8; ++g2) {
                pk[g2] = pack2(sj0[2 * g2], sj0[2 * g2 + 1]);
                X[g2] = (unsigned int)__shfl_xor((int)pk[g2], 32, 64);
            }
            u32x4 f0 = {hf ? X[2] : pk[0], hf ? X[3] : pk[1], hf ? pk[2] : X[0], hf ? pk[3] : X[1]};
            u32x4 f1 = {hf ? X[6] : pk[4], hf ? X[7] : pk[5], hf ? pk[6] : X[4], hf ? pk[7] : X[5]};
            pf[0] = __builtin_bit_cast(bf16x8, f0);
            pf[1] = __builtin_bit_cast(bf16x8, f1);
            #pragma unroll
            for (int g2 = 0; g2 < 8; ++g2) {
                pk[g2] = pack2(sj1[2 * g2], sj1[2 * g2 + 1]);
                X[g2] = (unsigned int)__shfl_xor((int)pk[g2], 32, 64);
            }
            u32x4 f2 = {hf ? X[2] : pk[0], hf ? X[3] : pk[1], hf ? pk[2] : X[0], hf ? pk[3] : X[1]};
            u32x4 f3 = {hf ? X[6] : pk[4], hf ? X[7] : pk[5], hf ? pk[6] : X[4], hf ? pk[7] : X[5]};
            pf[2] = __builtin_bit_cast(bf16x8, f2);
            pf[3] = __builtin_bit_cast(bf16x8, f3);
        }

        #pragma unroll
        for (int jk = 0; jk < 4; ++jk)
            #pragma unroll
            for (int d = 0; d < 6; ++d) {
                bf16x8 vf = *(const bf16x8*)&lds[24576 + (size_t)((jk * 6 + d) * 64 + lane) * 8];
                o[d] = MFMA(vf, pf[jk], o[d]);
            }

        if (jt + 1 < 16) {
            __syncthreads();
            char* lp = (char*)lds + soff;
            #pragma unroll
            for (int cc = 0; cc < 6; ++cc) {
                *(u32x4*)(lp + cc * 1024)         = tr[cc];
                *(u32x4*)(lp + 24576 + cc * 1024) = tr[6 + cc];
                *(u32x4*)(lp + 49152 + cc * 1024) = tr[12 + cc];
            }
            __syncthreads();
        }
    }

    // ---- epilogue: write unnormalized bf16 partial O + (m,l) ----
    const int tI = bh * 64 + itq;
    u16* Op = Opart + ((size_t)(half * 1024 + tI) * 96) * 64 + lane;
    #pragma unroll
    for (int d = 0; d < 6; ++d)
        #pragma unroll
        for (int r = 0; r < 16; ++r)
            Op[(d * 16 + r) * 64] = b16(o[d][r]);
    float* mlp = MLp + (size_t)(half * 1024 + tI) * 128 + lane * 2;
    mlp[0] = m_run;
    mlp[1] = l_run;
}

// ---------------- K2b: combine j-halves -> att2 (split-pack frag layout) -----
// grid 256 blocks x 256 threads; wave handles one (bh,itq) tile
__global__ __launch_bounds__(256) void attn_combine(const u16* __restrict__ Opart,
                                                    const float* __restrict__ MLp,
                                                    unsigned int* __restrict__ att2) {
    const int tid = threadIdx.x, lane = tid & 63, w = tid >> 6, hf = lane >> 5;
    const int tI = blockIdx.x * 4 + w;     // 0..1023
    const int bh = tI >> 6, itq = tI & 63;
    const float* mla = MLp + (size_t)tI * 128 + lane * 2;
    const float* mlb = MLp + (size_t)(1024 + tI) * 128 + lane * 2;
    float ma = mla[0], la = mla[1];
    float mb = mlb[0], lb = mlb[1];
    float mm = fmaxf(ma, mb);
    float wa = exp2f(ma - mm), wb = exp2f(mb - mm);
    float inv = 1.0f / (la * wa + lb * wb);
    const u16* Oa = Opart + ((size_t)tI * 96) * 64 + lane;
    const u16* Ob = Opart + ((size_t)(1024 + tI) * 96) * 64 + lane;
    const int b2 = bh >> 3, hh = bh & 7;
    const int i31 = lane & 31;
    #pragma unroll
    for (int d = 0; d < 6; ++d)
        #pragma unroll
        for (int r = 0; r < 16; ++r) {
            float va = fb16(Oa[(d * 16 + r) * 64]);
            float vb = fb16(Ob[(d * 16 + r) * 64]);
            float v = (va * wa + vb * wb) * inv;
            int dc = d * 32 + (r & 3) + 8 * (r >> 2) + 4 * hf;
            int dd = dc / 3, cc = dc - dd * 3;
            int hd = hh * 64 + dd;
            int ks = hd >> 4, e = hd & 7;
            int ln = i31 | (((hd >> 3) & 1) << 5);
            size_t off = ((((size_t)(b2 * 3 + cc) * 32 + ks) * 64 + itq) * 512 + (size_t)ln * 8 + e);
            att2[off] = splitpack(v);
        }
}

// ---------------- K3: output projection, MFMA split-bf16, no LDS ----------------
__global__ __launch_bounds__(256) void out_mfma(const unsigned int* __restrict__ att2,
                                                const float* __restrict__ wo,
                                                float* __restrict__ out) {
    const int tid = threadIdx.x, lane = tid & 63, w = tid >> 6, hf = lane >> 5, l31 = lane & 31;
    const int o0 = blockIdx.x * 32;
    const int n5 = blockIdx.y * 4 + w;
    const int b = blockIdx.z;
    const float* wp = wo + (size_t)(o0 + l31) * 512 + hf * 8;
    const unsigned int* ap = att2 + ((size_t)(b * 3) * 2048 + n5) * 512 + (size_t)lane * 8;
    f32x16 acc[3] = {};
    #pragma unroll 2
    for (int ks = 0; ks < 32; ++ks) {
        bf16x8 wh, wl;
        {
            f32x4v t0 = *(const f32x4v*)(wp + ks * 16);
            f32x4v t1 = *(const f32x4v*)(wp + ks * 16 + 4);
            #pragma unroll
            for (int e = 0; e < 4; ++e) {
                { float v = t0[e]; __bf16 hi = (__bf16)v; wh[e] = hi; wl[e] = (__bf16)(v - (float)hi); }
                { float v = t1[e]; __bf16 hi = (__bf16)v; wh[4 + e] = hi; wl[4 + e] = (__bf16)(v - (float)hi); }
            }
        }
        #pragma unroll
        for (int c = 0; c < 3; ++c) {
            const unsigned int* pc = ap + (size_t)c * 1048576 + ks * 32768;
            u32x4 a0 = *(const u32x4*)pc;
            u32x4 a1 = *(const u32x4*)(pc + 4);
            union { bf16x8 v; u32x4 u; } H, Lo;
            H.u  = { (a0[0] & 0xffffu) | (a0[1] << 16), (a0[2] & 0xffffu) | (a0[3] << 16),
                     (a1[0] & 0xffffu) | (a1[1] << 16), (a1[2] & 0xffffu) | (a1[3] << 16) };
            Lo.u = { (a0[0] >> 16) | (a0[1] & 0xffff0000u), (a0[2] >> 16) | (a0[3] & 0xffff0000u),
                     (a1[0] >> 16) | (a1[1] & 0xffff0000u), (a1[2] >> 16) | (a1[3] & 0xffff0000u) };
            acc[c] = MFMA(H.v, wh, acc[c]);
            acc[c] = MFMA(Lo.v, wh, acc[c]);
            acc[c] = MFMA(H.v, wl, acc[c]);
        }
    }
    #pragma unroll
    for (int r = 0; r < 16; ++r) {
        int n = (n5 << 5) + (r & 3) + 8 * (r >> 2) + 4 * hf;
        size_t off = ((size_t)(b * 2048 + n) * 256 + o0 + l31) * 3;
        out[off]     = acc[0][r];
        out[off + 1] = acc[1][r];
        out[off + 2] = acc[2][r];
    }
}

extern "C" void kernel_launch(void* const* d_in, const int* in_sizes, int n_in,
                              void* d_out, int out_size, void* d_ws, size_t ws_size,
                              hipStream_t stream) {
    const float* x     = (const float*)d_in[0];
    const float* w_qkv = (const float*)d_in[1];
    const float* w_out = (const float*)d_in[2];
    float* out = (float*)d_out;

    const size_t NB = (size_t)16 * 2048 * 192;  // 6.29M elems
    u16* Qhi = (u16*)d_ws;
    u16* Qlo = Qhi + NB;
    u16* Khi = Qlo + NB;
    u16* Klo = Khi + NB;
    u16* Vf  = Klo + NB;
    u16* Opart = Vf + NB;                       // 2*NB u16 = 25.2MB
    float* MLp = (float*)(Opart + 2 * NB);      // 262144 floats = 1MB
    unsigned int* att2 = (unsigned int*)Qhi;    // reuses Qhi+Qlo (dead after attn)

    qkv_mfma<<<dim3(24, 16, 2), 256, 0, stream>>>(x, w_qkv, Qhi, Qlo, Khi, Klo, Vf);
    attn_mfma<<<dim3(512), 256, 0, stream>>>(Qhi, Qlo, Khi, Klo, Vf, Opart, MLp);
    attn_combine<<<dim3(256), 256, 0, stream>>>(Opart, MLp, att2);
    out_mfma<<<dim3(8, 16, 2), 256, 0, stream>>>(att2, w_out, out);
}